// Round 8
// baseline (375.267 us; speedup 1.0000x reference)
//
#include <hip/hip_runtime.h>
#include <math.h>

// PosteriorRotationLayer: B=1, T=2048, D=1024, H=16, d=64, Tc=2016
// Pipeline:
//   split_prep   : ctx -> bf16 hi/lo; Wkv -> transposed bf16 hi/lo
//   gemm_ln_mfma : kvn_{hi,lo}[h][s][d] = split_bf16(LN_d64(context @ Wkv + bkv))  (MFMA)
//   skq_mfma     : sk[h][t][s] = bf16(tanh(q_t . kvn[h][s]))  (A=kv, B=q -> s-contig stores)
//   rot2         : out = x + eps * (A - A^T) x   uniform 63-iter gather per (h,t,j)
// p(j,i) = j*(j-1)/2 + i  (tril_indices(d,-1) row-major)

#define NT 2048
#define ND 1024
#define NH 16
#define DH 64
#define TC 2016
#define MPAD 2048          // padded context rows (poison tail finite-tiny, stores guarded)
#define SPAD 2048          // padded s-rows in kvn bf16 buffers
#define EPS_ROT 0.01f
#define LN_EPS 1e-5f

typedef __attribute__((ext_vector_type(8))) short short8;    // 8 bf16 = 4 VGPR
typedef __attribute__((ext_vector_type(16))) float f32x16;   // MFMA 32x32 acc

__device__ inline unsigned short f32_to_bf16(float f) {  // RNE
    unsigned int b = __float_as_uint(f);
    unsigned int r = (b + 0x7FFFu + ((b >> 16) & 1u)) >> 16;
    return (unsigned short)r;
}
__device__ inline float bf16_to_f32(unsigned short u) {
    return __uint_as_float((unsigned int)u << 16);
}
// clamp-free tanh: 1 - 2/(e^{2x}+1). e=inf -> 1, e=0 -> -1; no NaN for finite x.
__device__ inline float tanh_fast(float x) {
    float e = __expf(2.f * x);
    return 1.f - 2.f * __builtin_amdgcn_rcpf(e + 1.f);
}
__device__ inline void split_bf(float v, unsigned short& hi, unsigned short& lo) {
    hi = f32_to_bf16(v);
    lo = f32_to_bf16(v - bf16_to_f32(hi));
}

// ---------------- kernel 0: split ctx -> hi/lo bf16 rows; Wkv -> transposed hi/lo
__global__ __launch_bounds__(256) void split_prep(const float* __restrict__ ctx,
                                                  const float* __restrict__ Wkv,
                                                  unsigned short* __restrict__ ch,
                                                  unsigned short* __restrict__ cl,
                                                  unsigned short* __restrict__ wh,
                                                  unsigned short* __restrict__ wl) {
    __shared__ float ld[64][68];
    const int bid = blockIdx.x, tid = threadIdx.x;
    if (bid < TC) {                       // ctx row bid
        const float4 v = *(const float4*)&ctx[(size_t)bid * ND + tid * 4];
        ushort4 hv, lv;
        split_bf(v.x, hv.x, lv.x); split_bf(v.y, hv.y, lv.y);
        split_bf(v.z, hv.z, lv.z); split_bf(v.w, hv.w, lv.w);
        *(ushort4*)&ch[(size_t)bid * ND + tid * 4] = hv;
        *(ushort4*)&cl[(size_t)bid * ND + tid * 4] = lv;
    } else {                              // Wkv 64x64 tile transpose
        const int b2 = bid - TC;          // 0..255
        const int r0 = (b2 >> 4) * 64, c0 = (b2 & 15) * 64;
#pragma unroll
        for (int it = 0; it < 4; ++it) {
            int row = (tid >> 4) + it * 16, c4 = tid & 15;
            *(float4*)&ld[row][c4 * 4] =
                *(const float4*)&Wkv[(size_t)(r0 + row) * ND + c0 + c4 * 4];
        }
        __syncthreads();
#pragma unroll
        for (int it = 0; it < 4; ++it) {
            int n = (tid >> 4) + it * 16;          // local out col
            int k4 = (tid & 15) * 4;
            ushort4 hv, lv;
            split_bf(ld[k4 + 0][n], hv.x, lv.x);
            split_bf(ld[k4 + 1][n], hv.y, lv.y);
            split_bf(ld[k4 + 2][n], hv.z, lv.z);
            split_bf(ld[k4 + 3][n], hv.w, lv.w);
            size_t o = (size_t)(c0 + n) * ND + r0 + k4;
            *(ushort4*)&wh[o] = hv;
            *(ushort4*)&wl[o] = lv;
        }
    }
}

// ---------------- kernel 1: MFMA GEMM + fused LayerNorm -> kvn hi/lo
// grid (NH, MPAD/64). 256 thr = 4 waves, 2x2 quadrants of 32x32. K=1024, dbuf K-loop.
__global__ __launch_bounds__(256) void gemm_ln_mfma(const unsigned short* __restrict__ ch,
                                                    const unsigned short* __restrict__ cl,
                                                    const unsigned short* __restrict__ wh,
                                                    const unsigned short* __restrict__ wl,
                                                    const float* __restrict__ bkv,
                                                    const float* __restrict__ gamma,
                                                    const float* __restrict__ beta,
                                                    unsigned short* __restrict__ kvh,
                                                    unsigned short* __restrict__ kvl) {
    __shared__ float cbuf[64][68];
    const int tid = threadIdx.x;
    const int h = blockIdx.x;                 // n-tile == head
    const int m0 = blockIdx.y * 64;
    const int lane = tid & 63, wid = tid >> 6;
    const int wr = wid >> 1, wc = wid & 1;
    const int lrow = lane & 31, khalf = lane >> 5;

    const unsigned short* pah = ch + (size_t)(m0 + wr * 32 + lrow) * ND + khalf * 8;
    const unsigned short* pal = cl + (size_t)(m0 + wr * 32 + lrow) * ND + khalf * 8;
    const unsigned short* pbh = wh + (size_t)(h * 64 + wc * 32 + lrow) * ND + khalf * 8;
    const unsigned short* pbl = wl + (size_t)(h * 64 + wc * 32 + lrow) * ND + khalf * 8;

    f32x16 acc0 = (f32x16)(0.0f), acc1 = (f32x16)(0.0f);
    short8 a0h, a0l, b0h, b0l, a1h, a1l, b1h, b1l;
    a0h = *(const short8*)&pah[0]; a0l = *(const short8*)&pal[0];
    b0h = *(const short8*)&pbh[0]; b0l = *(const short8*)&pbl[0];
#pragma unroll
    for (int kt = 0; kt < 64; kt += 2) {      // 64 K-steps of 16, dbuf pairs
        a1h = *(const short8*)&pah[(kt + 1) * 16]; a1l = *(const short8*)&pal[(kt + 1) * 16];
        b1h = *(const short8*)&pbh[(kt + 1) * 16]; b1l = *(const short8*)&pbl[(kt + 1) * 16];
        acc0 = __builtin_amdgcn_mfma_f32_32x32x16_bf16(a0h, b0h, acc0, 0, 0, 0);
        acc0 = __builtin_amdgcn_mfma_f32_32x32x16_bf16(a0h, b0l, acc0, 0, 0, 0);
        acc0 = __builtin_amdgcn_mfma_f32_32x32x16_bf16(a0l, b0h, acc0, 0, 0, 0);
        if (kt + 2 < 64) {
            a0h = *(const short8*)&pah[(kt + 2) * 16]; a0l = *(const short8*)&pal[(kt + 2) * 16];
            b0h = *(const short8*)&pbh[(kt + 2) * 16]; b0l = *(const short8*)&pbl[(kt + 2) * 16];
        }
        acc1 = __builtin_amdgcn_mfma_f32_32x32x16_bf16(a1h, b1h, acc1, 0, 0, 0);
        acc1 = __builtin_amdgcn_mfma_f32_32x32x16_bf16(a1h, b1l, acc1, 0, 0, 0);
        acc1 = __builtin_amdgcn_mfma_f32_32x32x16_bf16(a1l, b1h, acc1, 0, 0, 0);
    }
    acc0 = acc0 + acc1;
    const float bias = bkv[h * 64 + wc * 32 + lrow];
#pragma unroll
    for (int r = 0; r < 16; ++r) {            // bounce C to LDS (2/bank, free)
        int mm = wr * 32 + (r & 3) + 8 * (r >> 2) + 4 * khalf;
        cbuf[mm][wc * 32 + lrow] = acc0[r] + bias;
    }
    __syncthreads();
    // LN over 64-wide rows: 4 threads/row x 16 vals
    const int row = tid >> 2, part = tid & 3;
    float4 v[4];
#pragma unroll
    for (int c = 0; c < 4; ++c) v[c] = *(const float4*)&cbuf[row][part * 16 + c * 4];
    float s = 0.f;
#pragma unroll
    for (int c = 0; c < 4; ++c) s += v[c].x + v[c].y + v[c].z + v[c].w;
    s += __shfl_xor(s, 1); s += __shfl_xor(s, 2);
    const float mean = s * (1.f / 64.f);
    float q = 0.f;
#pragma unroll
    for (int c = 0; c < 4; ++c) {
        v[c].x -= mean; v[c].y -= mean; v[c].z -= mean; v[c].w -= mean;
        q += v[c].x * v[c].x + v[c].y * v[c].y + v[c].z * v[c].z + v[c].w * v[c].w;
    }
    q += __shfl_xor(q, 1); q += __shfl_xor(q, 2);
    const float inv = 1.f / (sqrtf(q * (1.f / 63.f)) + LN_EPS);   // ddof=1, /(std+eps)
    const int srow = m0 + row;
    if (srow < TC) {
        const size_t base = ((size_t)h * SPAD + srow) * DH + part * 16;
#pragma unroll
        for (int c = 0; c < 4; ++c) {
            const float4 g4 = *(const float4*)&gamma[part * 16 + c * 4];
            const float4 b4 = *(const float4*)&beta[part * 16 + c * 4];
            ushort4 hv, lv;
            split_bf(g4.x * v[c].x * inv + b4.x, hv.x, lv.x);
            split_bf(g4.y * v[c].y * inv + b4.y, hv.y, lv.y);
            split_bf(g4.z * v[c].z * inv + b4.z, hv.z, lv.z);
            split_bf(g4.w * v[c].w * inv + b4.w, hv.w, lv.w);
            *(ushort4*)&kvh[base + c * 4] = hv;
            *(ushort4*)&kvl[base + c * 4] = lv;
        }
    }
}

// ---------------- kernel 2: q-proj + split-bf16 MFMA scores -> sk (bf16)
// grid (cur/64, 2 s-halves, H). A=kv (rows=s), B=q (cols=t): lane stores 4x ushort4
// of consecutive s. Double-buffered kv loads, two MFMA chains.
__global__ __launch_bounds__(256) void skq_mfma(const float* __restrict__ x,
                                                const float* __restrict__ Wq,
                                                const float* __restrict__ bq,
                                                const unsigned short* __restrict__ kvh,
                                                const unsigned short* __restrict__ kvl,
                                                unsigned short* __restrict__ sk,
                                                int t_base, int curT) {
    __shared__ float xs[64][68];
    __shared__ unsigned short qh[64][72];
    __shared__ unsigned short ql[64][72];
    const int tid = threadIdx.x;
    const int h = blockIdx.z;
    const int sHalf = blockIdx.y;
    const int tblk = blockIdx.x * 64;

    // stage x tile 64x64
#pragma unroll
    for (int p = 0; p < 4; ++p) {
        int idx = p * 256 + tid, t = idx >> 4, c4 = idx & 15;
        *(float4*)&xs[t][c4 * 4] =
            *(const float4*)&x[(size_t)(t_base + tblk + t) * ND + h * DH + c4 * 4];
    }
    __syncthreads();
    // q = xs @ Wq + bq, split hi/lo, layout q[t][k]
#pragma unroll
    for (int p = 0; p < 4; ++p) {
        int u = p * 256 + tid, t = u >> 4, j4 = u & 15;
        float4 a = *(const float4*)&bq[j4 * 4];
        for (int i = 0; i < DH; ++i) {
            float xv = xs[t][i];
            const float4 w = *(const float4*)&Wq[i * DH + j4 * 4];
            a.x += xv * w.x; a.y += xv * w.y; a.z += xv * w.z; a.w += xv * w.w;
        }
        ushort4 hv, lv;
        split_bf(a.x, hv.x, lv.x); split_bf(a.y, hv.y, lv.y);
        split_bf(a.z, hv.z, lv.z); split_bf(a.w, hv.w, lv.w);
        *(ushort4*)&qh[t][j4 * 4] = hv;
        *(ushort4*)&ql[t][j4 * 4] = lv;
    }
    __syncthreads();

    const int lane = tid & 63, wid = tid >> 6;
    const int wr = wid >> 1, wc = wid & 1;     // wr: s-half of step, wc: t-half
    const int lrow = lane & 31;
    const int khalf = lane >> 5;

    // B-frags (q) fixed per block: col t = wc*32 + lrow
    short8 Bh[4], Bl[4];
#pragma unroll
    for (int ks = 0; ks < 4; ++ks) {
        Bh[ks] = *(const short8*)&qh[wc * 32 + lrow][ks * 16 + khalf * 8];
        Bl[ks] = *(const short8*)&ql[wc * 32 + lrow][ks * 16 + khalf * 8];
    }

    const unsigned short* pah =
        kvh + ((size_t)h * SPAD + sHalf * 1024 + wr * 32 + lrow) * DH + khalf * 8;
    const unsigned short* pal =
        kvl + ((size_t)h * SPAD + sHalf * 1024 + wr * 32 + lrow) * DH + khalf * 8;
    unsigned short* outp = sk + ((size_t)h * curT + (tblk + wc * 32 + lrow)) * (size_t)TC;

    auto loadA = [&](short8* Ah_, short8* Al_, int st_) {
        const size_t so = (size_t)st_ * 64 * DH;
#pragma unroll
        for (int ks = 0; ks < 4; ++ks) {
            Ah_[ks] = *(const short8*)&pah[so + ks * 16];
            Al_[ks] = *(const short8*)&pal[so + ks * 16];
        }
    };
    auto computeStore = [&](short8* Ah_, short8* Al_, int st_) {
        f32x16 acc0 = (f32x16)(0.0f), acc1 = (f32x16)(0.0f);
#pragma unroll
        for (int ks = 0; ks < 2; ++ks) {      // two independent chains
            acc0 = __builtin_amdgcn_mfma_f32_32x32x16_bf16(Ah_[ks], Bh[ks], acc0, 0, 0, 0);
            acc0 = __builtin_amdgcn_mfma_f32_32x32x16_bf16(Ah_[ks], Bl[ks], acc0, 0, 0, 0);
            acc0 = __builtin_amdgcn_mfma_f32_32x32x16_bf16(Al_[ks], Bh[ks], acc0, 0, 0, 0);
            acc1 = __builtin_amdgcn_mfma_f32_32x32x16_bf16(Ah_[ks + 2], Bh[ks + 2], acc1, 0, 0, 0);
            acc1 = __builtin_amdgcn_mfma_f32_32x32x16_bf16(Ah_[ks + 2], Bl[ks + 2], acc1, 0, 0, 0);
            acc1 = __builtin_amdgcn_mfma_f32_32x32x16_bf16(Al_[ks + 2], Bh[ks + 2], acc1, 0, 0, 0);
        }
        acc0 = acc0 + acc1;
        const int sq = sHalf * 1024 + st_ * 64 + wr * 32;   // quadrant s-base
        if (sq < TC) {                                      // wave-uniform tail guard
#pragma unroll
            for (int g = 0; g < 4; ++g) {                   // 4 consecutive s per group
                ushort4 v;
                v.x = f32_to_bf16(tanh_fast(acc0[4 * g + 0]));
                v.y = f32_to_bf16(tanh_fast(acc0[4 * g + 1]));
                v.z = f32_to_bf16(tanh_fast(acc0[4 * g + 2]));
                v.w = f32_to_bf16(tanh_fast(acc0[4 * g + 3]));
                *(ushort4*)&outp[sq + 8 * g + 4 * khalf] = v;
            }
        }
    };

    short8 A0h[4], A0l[4], A1h[4], A1l[4];
    loadA(A0h, A0l, 0);
#pragma unroll
    for (int st = 0; st < 16; st += 2) {
        loadA(A1h, A1l, st + 1);
        computeStore(A0h, A0l, st);
        if (st + 2 < 16) loadA(A0h, A0l, st + 2);
        computeStore(A1h, A1l, st + 1);
    }
}

// ---------------- kernel 3: rotation. 4 waves/block, wave = one (h,t).
__global__ __launch_bounds__(256) void rot2_kernel(const float* __restrict__ x,
                                                   const unsigned short* __restrict__ sk,
                                                   float* __restrict__ out,
                                                   int t_base, int curT) {
    __shared__ uint4 skbuf4[4][252];   // 4 x 2016 bf16
    __shared__ float xsr[4][68];
    const int lane = threadIdx.x & 63;
    const int w = threadIdx.x >> 6;
    const int u = blockIdx.x * 4 + w;
    const int tl = u >> 4;
    const int h = u & 15;

    {
        const uint4* src = (const uint4*)(sk + ((size_t)h * curT + tl) * (size_t)TC);
        for (int c = lane; c < 252; c += 64) skbuf4[w][c] = src[c];
    }
    const float xj = x[(size_t)(t_base + tl) * ND + h * DH + lane];
    xsr[w][lane] = xj;
    __syncthreads();

    const unsigned short* skw = (const unsigned short*)&skbuf4[w][0];
    const int j = lane;
    const int jb = (j * (j - 1)) >> 1;
    float acc = 0.f;
    int tri = 0;
#pragma unroll 7
    for (int k = 0; k < 63; ++k) {
        tri += k;
        const bool cond = k < j;
        const int idx = cond ? (jb + k) : (tri + j);
        const float xi = xsr[w][cond ? k : (k + 1)];
        const float sv = __uint_as_float((unsigned int)skw[idx] << 16);
        acc = fmaf(sv, cond ? xi : -xi, acc);
    }
    out[(size_t)(t_base + tl) * ND + h * DH + j] = xj + EPS_ROT * acc;
}

extern "C" void kernel_launch(void* const* d_in, const int* in_sizes, int n_in,
                              void* d_out, int out_size, void* d_ws, size_t ws_size,
                              hipStream_t stream) {
    const float* x     = (const float*)d_in[0];
    const float* ctx   = (const float*)d_in[1];
    const float* Wq    = (const float*)d_in[2];
    const float* bq    = (const float*)d_in[3];
    const float* Wkv   = (const float*)d_in[4];
    const float* bkv   = (const float*)d_in[5];
    const float* gamma = (const float*)d_in[6];
    const float* beta  = (const float*)d_in[7];
    float* outp = (float*)d_out;

    // ws layout: kvh kvl | ctxh ctxl | wh wl | sk
    unsigned short* kvh  = (unsigned short*)d_ws;             // NH*SPAD*DH
    unsigned short* kvl  = kvh + (size_t)NH * SPAD * DH;
    unsigned short* ctxh = kvl + (size_t)NH * SPAD * DH;      // MPAD*ND
    unsigned short* ctxl = ctxh + (size_t)MPAD * ND;
    unsigned short* wh   = ctxl + (size_t)MPAD * ND;          // ND*ND
    unsigned short* wl   = wh + (size_t)ND * ND;
    unsigned short* wend = wl + (size_t)ND * ND;
    size_t fixed_bytes = (size_t)((char*)wend - (char*)d_ws);
    size_t off = (fixed_bytes + 255) & ~(size_t)255;
    unsigned short* skbuf = (unsigned short*)((char*)d_ws + off);
    size_t avail = (ws_size > off) ? (ws_size - off) : 0;
    size_t per_tok = (size_t)NH * TC * 2;                     // 64512 B / token
    int slice = (int)((avail / per_tok) & ~(size_t)63);
    if (slice > NT) slice = NT;
    if (slice < 64) slice = 64;

    split_prep<<<dim3(TC + 256), 256, 0, stream>>>(ctx, Wkv, ctxh, ctxl, wh, wl);
    gemm_ln_mfma<<<dim3(NH, MPAD / 64), 256, 0, stream>>>(ctxh, ctxl, wh, wl,
                                                          bkv, gamma, beta, kvh, kvl);

    for (int t0 = 0; t0 < NT; t0 += slice) {
        int curt = (NT - t0 < slice) ? (NT - t0) : slice;
        skq_mfma<<<dim3(curt / 64, 2, NH), 256, 0, stream>>>(x, Wq, bq, kvh, kvl, skbuf, t0, curt);
        rot2_kernel<<<dim3(curt * 4), 256, 0, stream>>>(x, skbuf, outp, t0, curt);
    }
}

// Round 10
// 254.884 us; speedup vs baseline: 1.4723x; 1.4723x over previous
//
#include <hip/hip_runtime.h>
#include <math.h>

// PosteriorRotationLayer: B=1, T=2048, D=1024, H=16, d=64, Tc=2016
// Round 9: coalesced k-tiled layouts + global_load_lds staging + XOR-swizzled LDS reads.
//   split_prep   : ctx -> ct[kb][m][128] (hi|lo bf16), Wkv^T -> wt[kb][n][128]
//   gemm_ln_mfma : kvt[h][s][128] = split_bf16(LN_d64(context @ Wkv + bkv)), LDS-staged MFMA
//   skq_mfma     : sk[h][t][s] = bf16(tanh(q_t . kvn[h][s])), kv LDS-staged, full-s per block
//   rot2         : out = x + eps * (A - A^T) x   uniform 63-iter gather per (h,t,j)

#define NT 2048
#define ND 1024
#define NH 16
#define DH 64
#define TC 2016
#define MPAD 2048
#define SPAD 2048
#define EPS_ROT 0.01f
#define LN_EPS 1e-5f

typedef __attribute__((ext_vector_type(8))) short short8;    // 8 bf16 = 4 VGPR
typedef __attribute__((ext_vector_type(16))) float f32x16;   // MFMA 32x32 acc

__device__ inline unsigned short f32_to_bf16(float f) {  // RNE
    unsigned int b = __float_as_uint(f);
    unsigned int r = (b + 0x7FFFu + ((b >> 16) & 1u)) >> 16;
    return (unsigned short)r;
}
__device__ inline float bf16_to_f32(unsigned short u) {
    return __uint_as_float((unsigned int)u << 16);
}
__device__ inline float tanh_fast(float x) {   // 1 - 2/(e^2x+1): saturates, no NaN
    float e = __expf(2.f * x);
    return 1.f - 2.f * __builtin_amdgcn_rcpf(e + 1.f);
}
__device__ inline void split_bf(float v, unsigned short& hi, unsigned short& lo) {
    hi = f32_to_bf16(v);
    lo = f32_to_bf16(v - bf16_to_f32(hi));
}
// async 16B global->LDS (coalesced: wave dest = uniform base + lane*16)
__device__ inline void gll16(const void* g, void* l) {
    __builtin_amdgcn_global_load_lds(
        (const __attribute__((address_space(1))) unsigned int*)g,
        (__attribute__((address_space(3))) unsigned int*)l, 16, 0, 0);
}

// ---------------- kernel 0: re-layout. ct[kb][m][128]: cols 0-63 hi, 64-127 lo (bf16 of
// ctx[m][kb*64+k]); wt[kb][n][128] likewise for Wkv^T. Each 64x64 op tile = 16KB contiguous.
__global__ __launch_bounds__(256) void split_prep(const float* __restrict__ ctx,
                                                  const float* __restrict__ Wkv,
                                                  unsigned short* __restrict__ ct,
                                                  unsigned short* __restrict__ wt) {
    __shared__ float ld[64][68];
    const int bid = blockIdx.x, tid = threadIdx.x;
    if (bid < TC) {                       // ctx row bid
        const float4 v = *(const float4*)&ctx[(size_t)bid * ND + tid * 4];
        ushort4 hv, lv;
        split_bf(v.x, hv.x, lv.x); split_bf(v.y, hv.y, lv.y);
        split_bf(v.z, hv.z, lv.z); split_bf(v.w, hv.w, lv.w);
        const int kb = tid >> 4, kl = (tid & 15) * 4;
        size_t base = ((size_t)kb * MPAD + bid) * 128 + kl;
        *(ushort4*)&ct[base] = hv;
        *(ushort4*)&ct[base + 64] = lv;
    } else {                              // Wkv 64x64 tile transpose
        const int b2 = bid - TC;          // 0..255
        const int r0 = (b2 >> 4) * 64, c0 = (b2 & 15) * 64;   // r0: k, c0: n
#pragma unroll
        for (int it = 0; it < 4; ++it) {
            int row = (tid >> 4) + it * 16, c4 = tid & 15;
            *(float4*)&ld[row][c4 * 4] =
                *(const float4*)&Wkv[(size_t)(r0 + row) * ND + c0 + c4 * 4];
        }
        __syncthreads();
#pragma unroll
        for (int it = 0; it < 4; ++it) {
            int n = (tid >> 4) + it * 16;
            int k4 = tid & 15;
            ushort4 hv, lv;
            split_bf(ld[k4 * 4 + 0][n], hv.x, lv.x);
            split_bf(ld[k4 * 4 + 1][n], hv.y, lv.y);
            split_bf(ld[k4 * 4 + 2][n], hv.z, lv.z);
            split_bf(ld[k4 * 4 + 3][n], hv.w, lv.w);
            size_t base = ((size_t)(r0 >> 6) * ND + c0 + n) * 128 + k4 * 4;
            *(ushort4*)&wt[base] = hv;
            *(ushort4*)&wt[base + 64] = lv;
        }
    }
}

// ---------------- kernel 1: MFMA GEMM + fused LayerNorm -> kvt[h][s][128]
// grid (NH, MPAD/64). 4 waves, 2x2 quadrants. K-loop: 16 steps of 64, LDS dbuf staging.
__global__ __launch_bounds__(256) void gemm_ln_mfma(const unsigned short* __restrict__ ct,
                                                    const unsigned short* __restrict__ wt,
                                                    const float* __restrict__ bkv,
                                                    const float* __restrict__ gamma,
                                                    const float* __restrict__ beta,
                                                    unsigned short* __restrict__ kvt) {
    __shared__ unsigned short Abuf[2][64][128];   // 32KB
    __shared__ unsigned short Bbuf[2][64][128];   // 32KB
    const int tid = threadIdx.x;
    const int h = blockIdx.x;
    const int m0 = blockIdx.y * 64;
    const int lane = tid & 63, wid = tid >> 6;
    const int wr = wid >> 1, wc = wid & 1;
    const int lrow = lane & 31, khalf = lane >> 5;

    auto STAGE = [&](int b, int kb) {             // 2048 granules: A 1024 + B 1024
#pragma unroll
        for (int it = 0; it < 4; ++it) {
            int j = tid + it * 256;
            int row = j >> 4, g = (j & 15) ^ (row & 15);   // inverse-swizzled source
            gll16(ct + ((size_t)kb * MPAD + m0 + row) * 128 + g * 8,
                  (char*)&Abuf[b][0][0] + j * 16);
            gll16(wt + ((size_t)kb * ND + h * 64 + row) * 128 + g * 8,
                  (char*)&Bbuf[b][0][0] + j * 16);
        }
    };

    STAGE(0, 0);
    asm volatile("s_waitcnt vmcnt(0)" ::: "memory");
    __syncthreads();

    const int arow = wr * 32 + lrow;
    const int brow = wc * 32 + lrow;
    f32x16 acc0 = (f32x16)(0.0f), acc1 = (f32x16)(0.0f);
    int cur = 0;
    for (int kb = 0; kb < 16; ++kb) {
        if (kb + 1 < 16) STAGE(cur ^ 1, kb + 1);
        const unsigned short* ab = &Abuf[cur][0][0];
        const unsigned short* bb = &Bbuf[cur][0][0];
        short8 Ah[4], Al[4], Bh[4], Bl[4];
#pragma unroll
        for (int ks = 0; ks < 4; ++ks) {          // swizzled ds_read_b128
            int ga = (ks * 2 + khalf) ^ (arow & 15);
            int gal = (8 + ks * 2 + khalf) ^ (arow & 15);
            Ah[ks] = *(const short8*)(ab + arow * 128 + ga * 8);
            Al[ks] = *(const short8*)(ab + arow * 128 + gal * 8);
            int gb = (ks * 2 + khalf) ^ (brow & 15);
            int gbl = (8 + ks * 2 + khalf) ^ (brow & 15);
            Bh[ks] = *(const short8*)(bb + brow * 128 + gb * 8);
            Bl[ks] = *(const short8*)(bb + brow * 128 + gbl * 8);
        }
#pragma unroll
        for (int ks = 0; ks < 2; ++ks) {          // two independent 6-chains
            acc0 = __builtin_amdgcn_mfma_f32_32x32x16_bf16(Ah[ks], Bh[ks], acc0, 0, 0, 0);
            acc0 = __builtin_amdgcn_mfma_f32_32x32x16_bf16(Ah[ks], Bl[ks], acc0, 0, 0, 0);
            acc0 = __builtin_amdgcn_mfma_f32_32x32x16_bf16(Al[ks], Bh[ks], acc0, 0, 0, 0);
            acc1 = __builtin_amdgcn_mfma_f32_32x32x16_bf16(Ah[ks + 2], Bh[ks + 2], acc1, 0, 0, 0);
            acc1 = __builtin_amdgcn_mfma_f32_32x32x16_bf16(Ah[ks + 2], Bl[ks + 2], acc1, 0, 0, 0);
            acc1 = __builtin_amdgcn_mfma_f32_32x32x16_bf16(Al[ks + 2], Bh[ks + 2], acc1, 0, 0, 0);
        }
        asm volatile("s_waitcnt vmcnt(0)" ::: "memory");
        __syncthreads();
        cur ^= 1;
    }
    acc0 = acc0 + acc1;

    // epilogue: bounce C to LDS (overlay Abuf — all frag reads done), LN, store hi/lo
    float (*cbuf)[68] = (float (*)[68])&Abuf[0][0][0];   // 17.4KB <= 32KB
    const float bias = bkv[h * 64 + wc * 32 + lrow];
#pragma unroll
    for (int r = 0; r < 16; ++r) {
        int mm = wr * 32 + (r & 3) + 8 * (r >> 2) + 4 * khalf;
        cbuf[mm][wc * 32 + lrow] = acc0[r] + bias;
    }
    __syncthreads();
    const int row = tid >> 2, part = tid & 3;     // 4 threads per 64-wide row
    float4 v[4];
#pragma unroll
    for (int c = 0; c < 4; ++c) v[c] = *(const float4*)&cbuf[row][part * 16 + c * 4];
    float s = 0.f;
#pragma unroll
    for (int c = 0; c < 4; ++c) s += v[c].x + v[c].y + v[c].z + v[c].w;
    s += __shfl_xor(s, 1); s += __shfl_xor(s, 2);
    const float mean = s * (1.f / 64.f);
    float q = 0.f;
#pragma unroll
    for (int c = 0; c < 4; ++c) {
        v[c].x -= mean; v[c].y -= mean; v[c].z -= mean; v[c].w -= mean;
        q += v[c].x * v[c].x + v[c].y * v[c].y + v[c].z * v[c].z + v[c].w * v[c].w;
    }
    q += __shfl_xor(q, 1); q += __shfl_xor(q, 2);
    const float inv = 1.f / (sqrtf(q * (1.f / 63.f)) + LN_EPS);   // ddof=1, /(std+eps)
    const int srow = m0 + row;
    if (srow < TC) {
        const size_t base = ((size_t)h * SPAD + srow) * 128 + part * 16;
#pragma unroll
        for (int c = 0; c < 4; ++c) {
            const float4 g4 = *(const float4*)&gamma[part * 16 + c * 4];
            const float4 b4 = *(const float4*)&beta[part * 16 + c * 4];
            ushort4 hv, lv;
            split_bf(g4.x * v[c].x * inv + b4.x, hv.x, lv.x);
            split_bf(g4.y * v[c].y * inv + b4.y, hv.y, lv.y);
            split_bf(g4.z * v[c].z * inv + b4.z, hv.z, lv.z);
            split_bf(g4.w * v[c].w * inv + b4.w, hv.w, lv.w);
            *(ushort4*)&kvt[base + c * 4] = hv;
            *(ushort4*)&kvt[base + c * 4 + 64] = lv;
        }
    }
}

// ---------------- kernel 2: q-proj + MFMA scores -> sk[h][t][s] (bf16)
// grid (curT/64, NH). Block = 64 t x full 2016 s (q-proj once). kv LDS-staged dbuf.
// A=q (regs), B=kv (LDS): C col = s = lane -> lane-contiguous stores (64B segments).
__global__ __launch_bounds__(256) void skq_mfma(const float* __restrict__ x,
                                                const float* __restrict__ Wq,
                                                const float* __restrict__ bq,
                                                const unsigned short* __restrict__ kvt,
                                                unsigned short* __restrict__ sk,
                                                int t_base, int curT) {
    __shared__ unsigned short kvbuf[2][64][128];   // 32KB dbuf; xs overlays it in preamble
    __shared__ unsigned short qh[64][72];
    __shared__ unsigned short ql[64][72];
    const int tid = threadIdx.x;
    const int h = blockIdx.y;
    const int tblk = blockIdx.x * 64;

    {   // preamble: stage x, q-proj, split hi/lo into qh/ql
        float (*xs)[68] = (float (*)[68])&kvbuf[0][0][0];
#pragma unroll
        for (int p = 0; p < 4; ++p) {
            int idx = p * 256 + tid, t = idx >> 4, c4 = idx & 15;
            *(float4*)&xs[t][c4 * 4] =
                *(const float4*)&x[(size_t)(t_base + tblk + t) * ND + h * DH + c4 * 4];
        }
        __syncthreads();
#pragma unroll
        for (int p = 0; p < 4; ++p) {
            int u = p * 256 + tid, t = u >> 4, j4 = u & 15;
            float4 a = *(const float4*)&bq[j4 * 4];
            for (int i = 0; i < DH; ++i) {
                float xv = xs[t][i];
                const float4 w = *(const float4*)&Wq[i * DH + j4 * 4];
                a.x += xv * w.x; a.y += xv * w.y; a.z += xv * w.z; a.w += xv * w.w;
            }
            ushort4 hv, lv;
            split_bf(a.x, hv.x, lv.x); split_bf(a.y, hv.y, lv.y);
            split_bf(a.z, hv.z, lv.z); split_bf(a.w, hv.w, lv.w);
            *(ushort4*)&qh[t][j4 * 4] = hv;
            *(ushort4*)&ql[t][j4 * 4] = lv;
        }
        __syncthreads();
    }

    const int lane = tid & 63, wid = tid >> 6;
    const int wr = wid >> 1, wc = wid & 1;         // t-half, s-half
    const int lrow = lane & 31, khalf = lane >> 5;

    short8 Ah[4], Al[4];                           // q frags in regs, once per block
#pragma unroll
    for (int ks = 0; ks < 4; ++ks) {
        Ah[ks] = *(const short8*)&qh[wr * 32 + lrow][ks * 16 + khalf * 8];
        Al[ks] = *(const short8*)&ql[wr * 32 + lrow][ks * 16 + khalf * 8];
    }

    const unsigned short* kvtile = kvt + (size_t)h * SPAD * 128;
    auto STAGE = [&](int b, int s0) {              // 1024 granules (16KB), coalesced
#pragma unroll
        for (int it = 0; it < 4; ++it) {
            int j = tid + it * 256;
            int row = j >> 4, g = (j & 15) ^ (row & 15);
            gll16(kvtile + ((size_t)(s0 + row)) * 128 + g * 8,
                  (char*)&kvbuf[b][0][0] + j * 16);
        }
    };

    STAGE(0, 0);
    asm volatile("s_waitcnt vmcnt(0)" ::: "memory");
    __syncthreads();

    const int brow = wc * 32 + lrow;
    unsigned short* outbase = sk + ((size_t)h * curT + tblk + wr * 32) * (size_t)TC;
    int cur = 0;
    for (int st = 0; st < 32; ++st) {
        const int s0 = st * 64;
        if (st + 1 < 32) STAGE(cur ^ 1, s0 + 64);
        const unsigned short* bb = &kvbuf[cur][0][0];
        short8 Bh[4], Bl[4];
#pragma unroll
        for (int ks = 0; ks < 4; ++ks) {
            int gb = (ks * 2 + khalf) ^ (brow & 15);
            int gbl = (8 + ks * 2 + khalf) ^ (brow & 15);
            Bh[ks] = *(const short8*)(bb + brow * 128 + gb * 8);
            Bl[ks] = *(const short8*)(bb + brow * 128 + gbl * 8);
        }
        f32x16 acc0 = (f32x16)(0.0f), acc1 = (f32x16)(0.0f);
#pragma unroll
        for (int ks = 0; ks < 2; ++ks) {
            acc0 = __builtin_amdgcn_mfma_f32_32x32x16_bf16(Ah[ks], Bh[ks], acc0, 0, 0, 0);
            acc0 = __builtin_amdgcn_mfma_f32_32x32x16_bf16(Ah[ks], Bl[ks], acc0, 0, 0, 0);
            acc0 = __builtin_amdgcn_mfma_f32_32x32x16_bf16(Al[ks], Bh[ks], acc0, 0, 0, 0);
            acc1 = __builtin_amdgcn_mfma_f32_32x32x16_bf16(Ah[ks + 2], Bh[ks + 2], acc1, 0, 0, 0);
            acc1 = __builtin_amdgcn_mfma_f32_32x32x16_bf16(Ah[ks + 2], Bl[ks + 2], acc1, 0, 0, 0);
            acc1 = __builtin_amdgcn_mfma_f32_32x32x16_bf16(Al[ks + 2], Bh[ks + 2], acc1, 0, 0, 0);
        }
        acc0 = acc0 + acc1;
        const int sq = s0 + wc * 32;               // wave-uniform tail guard
        if (sq < TC) {
#pragma unroll
            for (int r = 0; r < 16; ++r) {         // col = s = lane -> 64B segments
                int rr = (r & 3) + 8 * (r >> 2) + 4 * khalf;
                outbase[(size_t)rr * TC + sq + lrow] = f32_to_bf16(tanh_fast(acc0[r]));
            }
        }
        asm volatile("s_waitcnt vmcnt(0)" ::: "memory");
        __syncthreads();
        cur ^= 1;
    }
}

// ---------------- kernel 3: rotation. 4 waves/block, wave = one (h,t).
__global__ __launch_bounds__(256) void rot2_kernel(const float* __restrict__ x,
                                                   const unsigned short* __restrict__ sk,
                                                   float* __restrict__ out,
                                                   int t_base, int curT) {
    __shared__ uint4 skbuf4[4][252];   // 4 x 2016 bf16
    __shared__ float xsr[4][68];
    const int lane = threadIdx.x & 63;
    const int w = threadIdx.x >> 6;
    const int u = blockIdx.x * 4 + w;
    const int tl = u >> 4;
    const int h = u & 15;

    {
        const uint4* src = (const uint4*)(sk + ((size_t)h * curT + tl) * (size_t)TC);
        for (int c = lane; c < 252; c += 64) skbuf4[w][c] = src[c];
    }
    const float xj = x[(size_t)(t_base + tl) * ND + h * DH + lane];
    xsr[w][lane] = xj;
    __syncthreads();

    const unsigned short* skw = (const unsigned short*)&skbuf4[w][0];
    const int j = lane;
    const int jb = (j * (j - 1)) >> 1;
    float acc = 0.f;
    int tri = 0;
#pragma unroll 7
    for (int k = 0; k < 63; ++k) {
        tri += k;
        const bool cond = k < j;
        const int idx = cond ? (jb + k) : (tri + j);
        const float xi = xsr[w][cond ? k : (k + 1)];
        const float sv = __uint_as_float((unsigned int)skw[idx] << 16);
        acc = fmaf(sv, cond ? xi : -xi, acc);
    }
    out[(size_t)(t_base + tl) * ND + h * DH + j] = xj + EPS_ROT * acc;
}

extern "C" void kernel_launch(void* const* d_in, const int* in_sizes, int n_in,
                              void* d_out, int out_size, void* d_ws, size_t ws_size,
                              hipStream_t stream) {
    const float* x     = (const float*)d_in[0];
    const float* ctx   = (const float*)d_in[1];
    const float* Wq    = (const float*)d_in[2];
    const float* bq    = (const float*)d_in[3];
    const float* Wkv   = (const float*)d_in[4];
    const float* bkv   = (const float*)d_in[5];
    const float* gamma = (const float*)d_in[6];
    const float* beta  = (const float*)d_in[7];
    float* outp = (float*)d_out;

    // ws layout: kvt | ct | wt | sk
    unsigned short* kvt = (unsigned short*)d_ws;              // NH*SPAD*128 = 8.4MB
    unsigned short* ct  = kvt + (size_t)NH * SPAD * 128;      // 16*MPAD*128 = 8.4MB
    unsigned short* wt  = ct + (size_t)16 * MPAD * 128;       // 16*ND*128   = 4.2MB
    unsigned short* wend = wt + (size_t)16 * ND * 128;
    size_t fixed_bytes = (size_t)((char*)wend - (char*)d_ws);
    size_t off = (fixed_bytes + 255) & ~(size_t)255;
    unsigned short* skbuf = (unsigned short*)((char*)d_ws + off);
    size_t avail = (ws_size > off) ? (ws_size - off) : 0;
    size_t per_tok = (size_t)NH * TC * 2;                     // 64512 B / token
    int slice = (int)((avail / per_tok) & ~(size_t)63);
    if (slice > NT) slice = NT;
    if (slice < 64) slice = 64;

    split_prep<<<dim3(TC + 256), 256, 0, stream>>>(ctx, Wkv, ct, wt);
    gemm_ln_mfma<<<dim3(NH, MPAD / 64), 256, 0, stream>>>(ct, wt, bkv, gamma, beta, kvt);

    for (int t0 = 0; t0 < NT; t0 += slice) {
        int curt = (NT - t0 < slice) ? (NT - t0) : slice;
        skq_mfma<<<dim3(curt / 64, NH), 256, 0, stream>>>(x, Wq, bq, kvt, skbuf, t0, curt);
        rot2_kernel<<<dim3(curt * 4), 256, 0, stream>>>(x, skbuf, outp, t0, curt);
    }
}

// Round 11
// 253.405 us; speedup vs baseline: 1.4809x; 1.0058x over previous
//
#include <hip/hip_runtime.h>
#include <math.h>

// PosteriorRotationLayer: B=1, T=2048, D=1024, H=16, d=64, Tc=2016
// Round 11: T4 counted-vmcnt in skq_mfma (stores never drained in-loop).
//   split_prep   : ctx -> ct[kb][m][128] (hi|lo bf16), Wkv^T -> wt[kb][n][128]
//   gemm_ln_mfma : kvt[h][s][128] = split_bf16(LN_d64(context @ Wkv + bkv)), LDS-staged MFMA
//   skq_mfma     : sk[h][t][s] = bf16(tanh(q_t . kvn[h][s])), raw-barrier + vmcnt(16) loop
//   rot2         : out = x + eps * (A - A^T) x   uniform 63-iter gather per (h,t,j)

#define NT 2048
#define ND 1024
#define NH 16
#define DH 64
#define TC 2016
#define MPAD 2048
#define SPAD 2048
#define SKP 2048           // padded sk row length (uniform stores -> counted vmcnt works)
#define EPS_ROT 0.01f
#define LN_EPS 1e-5f

typedef __attribute__((ext_vector_type(8))) short short8;    // 8 bf16 = 4 VGPR
typedef __attribute__((ext_vector_type(16))) float f32x16;   // MFMA 32x32 acc

__device__ inline unsigned short f32_to_bf16(float f) {  // RNE
    unsigned int b = __float_as_uint(f);
    unsigned int r = (b + 0x7FFFu + ((b >> 16) & 1u)) >> 16;
    return (unsigned short)r;
}
__device__ inline float bf16_to_f32(unsigned short u) {
    return __uint_as_float((unsigned int)u << 16);
}
__device__ inline float tanh_fast(float x) {   // 1 - 2/(e^2x+1): saturates, no NaN
    float e = __expf(2.f * x);
    return 1.f - 2.f * __builtin_amdgcn_rcpf(e + 1.f);
}
__device__ inline void split_bf(float v, unsigned short& hi, unsigned short& lo) {
    hi = f32_to_bf16(v);
    lo = f32_to_bf16(v - bf16_to_f32(hi));
}
// async 16B global->LDS (coalesced: wave dest = uniform base + lane*16)
__device__ inline void gll16(const void* g, void* l) {
    __builtin_amdgcn_global_load_lds(
        (const __attribute__((address_space(1))) unsigned int*)g,
        (__attribute__((address_space(3))) unsigned int*)l, 16, 0, 0);
}

// ---------------- kernel 0: re-layout. ct[kb][m][128]: cols 0-63 hi, 64-127 lo (bf16 of
// ctx[m][kb*64+k]); wt[kb][n][128] likewise for Wkv^T. Each 64x64 op tile = 16KB contiguous.
__global__ __launch_bounds__(256) void split_prep(const float* __restrict__ ctx,
                                                  const float* __restrict__ Wkv,
                                                  unsigned short* __restrict__ ct,
                                                  unsigned short* __restrict__ wt) {
    __shared__ float ld[64][68];
    const int bid = blockIdx.x, tid = threadIdx.x;
    if (bid < TC) {                       // ctx row bid
        const float4 v = *(const float4*)&ctx[(size_t)bid * ND + tid * 4];
        ushort4 hv, lv;
        split_bf(v.x, hv.x, lv.x); split_bf(v.y, hv.y, lv.y);
        split_bf(v.z, hv.z, lv.z); split_bf(v.w, hv.w, lv.w);
        const int kb = tid >> 4, kl = (tid & 15) * 4;
        size_t base = ((size_t)kb * MPAD + bid) * 128 + kl;
        *(ushort4*)&ct[base] = hv;
        *(ushort4*)&ct[base + 64] = lv;
    } else {                              // Wkv 64x64 tile transpose
        const int b2 = bid - TC;          // 0..255
        const int r0 = (b2 >> 4) * 64, c0 = (b2 & 15) * 64;   // r0: k, c0: n
#pragma unroll
        for (int it = 0; it < 4; ++it) {
            int row = (tid >> 4) + it * 16, c4 = tid & 15;
            *(float4*)&ld[row][c4 * 4] =
                *(const float4*)&Wkv[(size_t)(r0 + row) * ND + c0 + c4 * 4];
        }
        __syncthreads();
#pragma unroll
        for (int it = 0; it < 4; ++it) {
            int n = (tid >> 4) + it * 16;
            int k4 = tid & 15;
            ushort4 hv, lv;
            split_bf(ld[k4 * 4 + 0][n], hv.x, lv.x);
            split_bf(ld[k4 * 4 + 1][n], hv.y, lv.y);
            split_bf(ld[k4 * 4 + 2][n], hv.z, lv.z);
            split_bf(ld[k4 * 4 + 3][n], hv.w, lv.w);
            size_t base = ((size_t)(r0 >> 6) * ND + c0 + n) * 128 + k4 * 4;
            *(ushort4*)&wt[base] = hv;
            *(ushort4*)&wt[base + 64] = lv;
        }
    }
}

// ---------------- kernel 1: MFMA GEMM + fused LayerNorm -> kvt[h][s][128]
// grid (NH, MPAD/64). 4 waves, 2x2 quadrants. K-loop: 16 steps of 64, LDS dbuf staging.
__global__ __launch_bounds__(256) void gemm_ln_mfma(const unsigned short* __restrict__ ct,
                                                    const unsigned short* __restrict__ wt,
                                                    const float* __restrict__ bkv,
                                                    const float* __restrict__ gamma,
                                                    const float* __restrict__ beta,
                                                    unsigned short* __restrict__ kvt) {
    __shared__ unsigned short Abuf[2][64][128];   // 32KB
    __shared__ unsigned short Bbuf[2][64][128];   // 32KB
    const int tid = threadIdx.x;
    const int h = blockIdx.x;
    const int m0 = blockIdx.y * 64;
    const int lane = tid & 63, wid = tid >> 6;
    const int wr = wid >> 1, wc = wid & 1;
    const int lrow = lane & 31, khalf = lane >> 5;

    auto STAGE = [&](int b, int kb) {             // 2048 granules: A 1024 + B 1024
#pragma unroll
        for (int it = 0; it < 4; ++it) {
            int j = tid + it * 256;
            int row = j >> 4, g = (j & 15) ^ (row & 15);   // inverse-swizzled source
            gll16(ct + ((size_t)kb * MPAD + m0 + row) * 128 + g * 8,
                  (char*)&Abuf[b][0][0] + j * 16);
            gll16(wt + ((size_t)kb * ND + h * 64 + row) * 128 + g * 8,
                  (char*)&Bbuf[b][0][0] + j * 16);
        }
    };

    STAGE(0, 0);
    asm volatile("s_waitcnt vmcnt(0)" ::: "memory");
    __syncthreads();

    const int arow = wr * 32 + lrow;
    const int brow = wc * 32 + lrow;
    f32x16 acc0 = (f32x16)(0.0f), acc1 = (f32x16)(0.0f);
    int cur = 0;
    for (int kb = 0; kb < 16; ++kb) {
        if (kb + 1 < 16) STAGE(cur ^ 1, kb + 1);
        const unsigned short* ab = &Abuf[cur][0][0];
        const unsigned short* bb = &Bbuf[cur][0][0];
        short8 Ah[4], Al[4], Bh[4], Bl[4];
#pragma unroll
        for (int ks = 0; ks < 4; ++ks) {          // swizzled ds_read_b128
            int ga = (ks * 2 + khalf) ^ (arow & 15);
            int gal = (8 + ks * 2 + khalf) ^ (arow & 15);
            Ah[ks] = *(const short8*)(ab + arow * 128 + ga * 8);
            Al[ks] = *(const short8*)(ab + arow * 128 + gal * 8);
            int gb = (ks * 2 + khalf) ^ (brow & 15);
            int gbl = (8 + ks * 2 + khalf) ^ (brow & 15);
            Bh[ks] = *(const short8*)(bb + brow * 128 + gb * 8);
            Bl[ks] = *(const short8*)(bb + brow * 128 + gbl * 8);
        }
#pragma unroll
        for (int ks = 0; ks < 2; ++ks) {          // two independent 6-chains
            acc0 = __builtin_amdgcn_mfma_f32_32x32x16_bf16(Ah[ks], Bh[ks], acc0, 0, 0, 0);
            acc0 = __builtin_amdgcn_mfma_f32_32x32x16_bf16(Ah[ks], Bl[ks], acc0, 0, 0, 0);
            acc0 = __builtin_amdgcn_mfma_f32_32x32x16_bf16(Al[ks], Bh[ks], acc0, 0, 0, 0);
            acc1 = __builtin_amdgcn_mfma_f32_32x32x16_bf16(Ah[ks + 2], Bh[ks + 2], acc1, 0, 0, 0);
            acc1 = __builtin_amdgcn_mfma_f32_32x32x16_bf16(Ah[ks + 2], Bl[ks + 2], acc1, 0, 0, 0);
            acc1 = __builtin_amdgcn_mfma_f32_32x32x16_bf16(Al[ks + 2], Bh[ks + 2], acc1, 0, 0, 0);
        }
        asm volatile("s_waitcnt vmcnt(0)" ::: "memory");
        __syncthreads();
        cur ^= 1;
    }
    acc0 = acc0 + acc1;

    // epilogue: bounce C to LDS (overlay Abuf — all frag reads done), LN, store hi/lo
    float (*cbuf)[68] = (float (*)[68])&Abuf[0][0][0];   // 17.4KB <= 32KB
    const float bias = bkv[h * 64 + wc * 32 + lrow];
#pragma unroll
    for (int r = 0; r < 16; ++r) {
        int mm = wr * 32 + (r & 3) + 8 * (r >> 2) + 4 * khalf;
        cbuf[mm][wc * 32 + lrow] = acc0[r] + bias;
    }
    __syncthreads();
    const int row = tid >> 2, part = tid & 3;     // 4 threads per 64-wide row
    float4 v[4];
#pragma unroll
    for (int c = 0; c < 4; ++c) v[c] = *(const float4*)&cbuf[row][part * 16 + c * 4];
    float s = 0.f;
#pragma unroll
    for (int c = 0; c < 4; ++c) s += v[c].x + v[c].y + v[c].z + v[c].w;
    s += __shfl_xor(s, 1); s += __shfl_xor(s, 2);
    const float mean = s * (1.f / 64.f);
    float q = 0.f;
#pragma unroll
    for (int c = 0; c < 4; ++c) {
        v[c].x -= mean; v[c].y -= mean; v[c].z -= mean; v[c].w -= mean;
        q += v[c].x * v[c].x + v[c].y * v[c].y + v[c].z * v[c].z + v[c].w * v[c].w;
    }
    q += __shfl_xor(q, 1); q += __shfl_xor(q, 2);
    const float inv = 1.f / (sqrtf(q * (1.f / 63.f)) + LN_EPS);   // ddof=1, /(std+eps)
    const int srow = m0 + row;
    if (srow < TC) {
        const size_t base = ((size_t)h * SPAD + srow) * 128 + part * 16;
#pragma unroll
        for (int c = 0; c < 4; ++c) {
            const float4 g4 = *(const float4*)&gamma[part * 16 + c * 4];
            const float4 b4 = *(const float4*)&beta[part * 16 + c * 4];
            ushort4 hv, lv;
            split_bf(g4.x * v[c].x * inv + b4.x, hv.x, lv.x);
            split_bf(g4.y * v[c].y * inv + b4.y, hv.y, lv.y);
            split_bf(g4.z * v[c].z * inv + b4.z, hv.z, lv.z);
            split_bf(g4.w * v[c].w * inv + b4.w, hv.w, lv.w);
            *(ushort4*)&kvt[base + c * 4] = hv;
            *(ushort4*)&kvt[base + c * 4 + 64] = lv;
        }
    }
}

// ---------------- kernel 2: q-proj + MFMA scores -> sk[h][t][SKP] (bf16)
// grid (curT/64, NH). Block = 64 t x full s. kv LDS-staged dbuf.
// T4 loop: STAGE(next) -> ds_read+MFMA(cur) -> tanh+16 uniform stores -> vmcnt(16)
// (4 prefetch loads are the 20-16=4 oldest outstanding ops; stores fly across barrier).
__global__ __launch_bounds__(256) void skq_mfma(const float* __restrict__ x,
                                                const float* __restrict__ Wq,
                                                const float* __restrict__ bq,
                                                const unsigned short* __restrict__ kvt,
                                                unsigned short* __restrict__ sk,
                                                int t_base, int curT) {
    __shared__ unsigned short kvbuf[2][64][128];   // 32KB dbuf; xs overlays it in preamble
    __shared__ unsigned short qh[64][72];
    __shared__ unsigned short ql[64][72];
    const int tid = threadIdx.x;
    const int h = blockIdx.y;
    const int tblk = blockIdx.x * 64;

    {   // preamble: stage x, q-proj, split hi/lo into qh/ql
        float (*xs)[68] = (float (*)[68])&kvbuf[0][0][0];
#pragma unroll
        for (int p = 0; p < 4; ++p) {
            int idx = p * 256 + tid, t = idx >> 4, c4 = idx & 15;
            *(float4*)&xs[t][c4 * 4] =
                *(const float4*)&x[(size_t)(t_base + tblk + t) * ND + h * DH + c4 * 4];
        }
        __syncthreads();
#pragma unroll
        for (int p = 0; p < 4; ++p) {
            int u = p * 256 + tid, t = u >> 4, j4 = u & 15;
            float4 a = *(const float4*)&bq[j4 * 4];
            for (int i = 0; i < DH; ++i) {
                float xv = xs[t][i];
                const float4 w = *(const float4*)&Wq[i * DH + j4 * 4];
                a.x += xv * w.x; a.y += xv * w.y; a.z += xv * w.z; a.w += xv * w.w;
            }
            ushort4 hv, lv;
            split_bf(a.x, hv.x, lv.x); split_bf(a.y, hv.y, lv.y);
            split_bf(a.z, hv.z, lv.z); split_bf(a.w, hv.w, lv.w);
            *(ushort4*)&qh[t][j4 * 4] = hv;
            *(ushort4*)&ql[t][j4 * 4] = lv;
        }
        __syncthreads();
    }

    const int lane = tid & 63, wid = tid >> 6;
    const int wr = wid >> 1, wc = wid & 1;         // t-half, s-half
    const int lrow = lane & 31, khalf = lane >> 5;

    short8 Ah[4], Al[4];                           // q frags in regs, once per block
#pragma unroll
    for (int ks = 0; ks < 4; ++ks) {
        Ah[ks] = *(const short8*)&qh[wr * 32 + lrow][ks * 16 + khalf * 8];
        Al[ks] = *(const short8*)&ql[wr * 32 + lrow][ks * 16 + khalf * 8];
    }

    const unsigned short* kvtile = kvt + (size_t)h * SPAD * 128;
    auto STAGE = [&](int b, int s0) {              // 4 gll16/thread (16KB), coalesced
#pragma unroll
        for (int it = 0; it < 4; ++it) {
            int j = tid + it * 256;
            int row = j >> 4, g = (j & 15) ^ (row & 15);
            gll16(kvtile + ((size_t)(s0 + row)) * 128 + g * 8,
                  (char*)&kvbuf[b][0][0] + j * 16);
        }
    };

    STAGE(0, 0);
    asm volatile("s_waitcnt vmcnt(0)" ::: "memory");
    __syncthreads();

    const int brow = wc * 32 + lrow;
    unsigned short* outbase = sk + ((size_t)h * curT + tblk + wr * 32) * (size_t)SKP;
    int cur = 0;
    for (int st = 0; st < 32; ++st) {
        const int s0 = st * 64;
        if (st + 1 < 32) STAGE(cur ^ 1, s0 + 64);   // 4 loads, oldest outstanding
        const unsigned short* bb = &kvbuf[cur][0][0];
        short8 Bh[4], Bl[4];
#pragma unroll
        for (int ks = 0; ks < 4; ++ks) {
            int gb = (ks * 2 + khalf) ^ (brow & 15);
            int gbl = (8 + ks * 2 + khalf) ^ (brow & 15);
            Bh[ks] = *(const short8*)(bb + brow * 128 + gb * 8);
            Bl[ks] = *(const short8*)(bb + brow * 128 + gbl * 8);
        }
        f32x16 acc0 = (f32x16)(0.0f), acc1 = (f32x16)(0.0f);
#pragma unroll
        for (int ks = 0; ks < 2; ++ks) {
            acc0 = __builtin_amdgcn_mfma_f32_32x32x16_bf16(Ah[ks], Bh[ks], acc0, 0, 0, 0);
            acc0 = __builtin_amdgcn_mfma_f32_32x32x16_bf16(Ah[ks], Bl[ks], acc0, 0, 0, 0);
            acc0 = __builtin_amdgcn_mfma_f32_32x32x16_bf16(Al[ks], Bh[ks], acc0, 0, 0, 0);
            acc1 = __builtin_amdgcn_mfma_f32_32x32x16_bf16(Ah[ks + 2], Bh[ks + 2], acc1, 0, 0, 0);
            acc1 = __builtin_amdgcn_mfma_f32_32x32x16_bf16(Ah[ks + 2], Bl[ks + 2], acc1, 0, 0, 0);
            acc1 = __builtin_amdgcn_mfma_f32_32x32x16_bf16(Al[ks + 2], Bh[ks + 2], acc1, 0, 0, 0);
        }
        acc0 = acc0 + acc1;
        const int sq = s0 + wc * 32;
#pragma unroll
        for (int r = 0; r < 16; ++r) {             // 16 stores, uniform (padded row)
            int rr = (r & 3) + 8 * (r >> 2) + 4 * khalf;
            outbase[(size_t)rr * SKP + sq + lrow] = f32_to_bf16(tanh_fast(acc0[r]));
        }
        // T4: wait only until the 4 prefetch loads (oldest) retired; 16 stores in flight
        asm volatile("s_waitcnt vmcnt(16)" ::: "memory");
        __builtin_amdgcn_sched_barrier(0);
        __builtin_amdgcn_s_barrier();
        __builtin_amdgcn_sched_barrier(0);
        cur ^= 1;
    }
}

// ---------------- kernel 3: rotation. 4 waves/block, wave = one (h,t).
__global__ __launch_bounds__(256) void rot2_kernel(const float* __restrict__ x,
                                                   const unsigned short* __restrict__ sk,
                                                   float* __restrict__ out,
                                                   int t_base, int curT) {
    __shared__ uint4 skbuf4[4][252];   // 4 x 2016 bf16
    __shared__ float xsr[4][68];
    const int lane = threadIdx.x & 63;
    const int w = threadIdx.x >> 6;
    const int u = blockIdx.x * 4 + w;
    const int tl = u >> 4;
    const int h = u & 15;

    {
        const uint4* src = (const uint4*)(sk + ((size_t)h * curT + tl) * (size_t)SKP);
        for (int c = lane; c < 252; c += 64) skbuf4[w][c] = src[c];
    }
    const float xj = x[(size_t)(t_base + tl) * ND + h * DH + lane];
    xsr[w][lane] = xj;
    __syncthreads();

    const unsigned short* skw = (const unsigned short*)&skbuf4[w][0];
    const int j = lane;
    const int jb = (j * (j - 1)) >> 1;
    float acc = 0.f;
    int tri = 0;
#pragma unroll 7
    for (int k = 0; k < 63; ++k) {
        tri += k;
        const bool cond = k < j;
        const int idx = cond ? (jb + k) : (tri + j);
        const float xi = xsr[w][cond ? k : (k + 1)];
        const float sv = __uint_as_float((unsigned int)skw[idx] << 16);
        acc = fmaf(sv, cond ? xi : -xi, acc);
    }
    out[(size_t)(t_base + tl) * ND + h * DH + j] = xj + EPS_ROT * acc;
}

extern "C" void kernel_launch(void* const* d_in, const int* in_sizes, int n_in,
                              void* d_out, int out_size, void* d_ws, size_t ws_size,
                              hipStream_t stream) {
    const float* x     = (const float*)d_in[0];
    const float* ctx   = (const float*)d_in[1];
    const float* Wq    = (const float*)d_in[2];
    const float* bq    = (const float*)d_in[3];
    const float* Wkv   = (const float*)d_in[4];
    const float* bkv   = (const float*)d_in[5];
    const float* gamma = (const float*)d_in[6];
    const float* beta  = (const float*)d_in[7];
    float* outp = (float*)d_out;

    // ws layout: kvt | ct | wt | sk
    unsigned short* kvt = (unsigned short*)d_ws;              // NH*SPAD*128 = 8.4MB
    unsigned short* ct  = kvt + (size_t)NH * SPAD * 128;      // 16*MPAD*128 = 8.4MB
    unsigned short* wt  = ct + (size_t)16 * MPAD * 128;       // 16*ND*128   = 4.2MB
    unsigned short* wend = wt + (size_t)16 * ND * 128;
    size_t fixed_bytes = (size_t)((char*)wend - (char*)d_ws);
    size_t off = (fixed_bytes + 255) & ~(size_t)255;
    unsigned short* skbuf = (unsigned short*)((char*)d_ws + off);
    size_t avail = (ws_size > off) ? (ws_size - off) : 0;
    size_t per_tok = (size_t)NH * SKP * 2;                    // 65536 B / token (padded)
    int slice = (int)((avail / per_tok) & ~(size_t)63);
    if (slice > NT) slice = NT;
    if (slice < 64) slice = 64;

    split_prep<<<dim3(TC + 256), 256, 0, stream>>>(ctx, Wkv, ct, wt);
    gemm_ln_mfma<<<dim3(NH, MPAD / 64), 256, 0, stream>>>(ct, wt, bkv, gamma, beta, kvt);

    for (int t0 = 0; t0 < NT; t0 += slice) {
        int curt = (NT - t0 < slice) ? (NT - t0) : slice;
        skq_mfma<<<dim3(curt / 64, NH), 256, 0, stream>>>(x, Wq, bq, kvt, skbuf, t0, curt);
        rot2_kernel<<<dim3(curt * 4), 256, 0, stream>>>(x, skbuf, outp, t0, curt);
    }
}